// Round 10
// baseline (263.925 us; speedup 1.0000x reference)
//
#include <hip/hip_runtime.h>
#include <hip/hip_fp16.h>
#include <stdint.h>

// Problem dims (fixed by reference)
// Reference dtypes: x fp16, bias fp16, out fp16 -> harness passes/reads FLOAT32.
// packed_w int32 (8192 x 512), 16 two-bit codes per word, values {0,1,3}.
#define M_DIM 1024
#define N_DIM 8192
#define K_DIM 8192
#define KP    (K_DIM / 16)   // 512 packed int32 words per weight row

#define BK 64
#define B_STRIDE 144          // fallback kernels only

// Workspace layout:
//   [0, 16 MiB)   : transposed fp16 A (cvt_x_t):
//       mt(8):2MiB | kt(128):16KiB | i32(4):4KiB | ks(4):1KiB | q(2):512 | r(32):16
//   [16, 32 MiB)  : repacked W half-words (repack_w):
//       nt(256) x kt(128) x lane(64) x uint2; lane = half*32 + (n&31)
//       uint2 = { h(ks0)|h(ks1)<<16, h(ks2)|h(ks3)<<16 }, h = 16-bit half-word (8 codes)
#define MT_STRIDE 2097152
#define KT_STRIDE 16384
#define BW_OFF    ((size_t)16 * 1024 * 1024)

typedef _Float16 half8   __attribute__((ext_vector_type(8)));
typedef __fp16   fp16x2  __attribute__((ext_vector_type(2)));
typedef float    f32x4   __attribute__((ext_vector_type(4)));
typedef float    f32x16  __attribute__((ext_vector_type(16)));

__device__ __forceinline__ uint32_t cvt2(float a, float b) {
  fp16x2 p = __builtin_amdgcn_cvt_pkrtz(a, b);   // RTZ exact: values are fp16-representable
  return __builtin_bit_cast(uint32_t, p);
}

// ---- in-register half-word ternary decode (R9-verified math, h pre-isolated) ----
// h = 16 bits = 8 codes (bits 2i). W-spread -> sel bytes [c0..c3],[c4..c7] -> T-table perm.
// T bytes [0x00,0x3C,0x06,0x42] = fp16 hi-bytes of {0,1,2,3} (low byte always 0).
__device__ __forceinline__ half8 dec_h(uint32_t h) {
  const uint32_t T = 0x42063C00u;
  uint32_t W  = (h & 0x3333u) | ((h << 14) & 0x33330000u);
  uint32_t c0 = __builtin_amdgcn_perm(0u, W, 0x04040200u);  // W.b0 | W.b2<<8
  uint32_t c1 = __builtin_amdgcn_perm(0u, W, 0x04040301u);  // W.b1 | W.b3<<8
  uint32_t s0 = (c0 * 0x1001u) & 0x03030303u;               // [c0,c1,c2,c3]
  uint32_t s1 = (c1 * 0x1001u) & 0x03030303u;               // [c4,c5,c6,c7]
  uint32_t P0 = __builtin_amdgcn_perm(0u, T, s0);
  uint32_t P1 = __builtin_amdgcn_perm(0u, T, s1);
  uint4 v;
  v.x = __builtin_amdgcn_perm(P0, 0u, 0x05000400u);  // fp16(c0), fp16(c1)
  v.y = __builtin_amdgcn_perm(P0, 0u, 0x07000600u);
  v.z = __builtin_amdgcn_perm(P1, 0u, 0x05000400u);
  v.w = __builtin_amdgcn_perm(P1, 0u, 0x07000600u);
  return __builtin_bit_cast(half8, v);
}

// ---- pre-pass 1: x f32 -> fp16, transposed-tiled (R8/R9 verified) ----
__global__ __launch_bounds__(256)
void cvt_x_t(const float* __restrict__ x, char* __restrict__ xhT) {
  __shared__ __align__(16) char st[16384];
  const int b  = blockIdx.x;
  const int mt = b >> 7, kt = b & 127;
  const int t  = threadIdx.x;
#pragma unroll
  for (int p = 0; p < 8; ++p) {
    int f   = t + 256 * p;
    int R   = f >> 4;
    int cc4 = f & 15;
    float4 v = *(const float4*)(x + (size_t)(mt * 128 + R) * K_DIM + kt * 64 + cc4 * 4);
    uint32_t w0 = cvt2(v.x, v.y), w1 = cvt2(v.z, v.w);
    int c8 = cc4 >> 1, hh = cc4 & 1;
    int i32 = R >> 5, r = R & 31, ks = c8 >> 1, q = c8 & 1;
    *(uint2*)(st + i32 * 4096 + ks * 1024 + q * 512 + r * 16 + hh * 8) = make_uint2(w0, w1);
  }
  __syncthreads();
  char* outb = xhT + (size_t)mt * MT_STRIDE + (size_t)kt * KT_STRIDE;
#pragma unroll
  for (int e = 0; e < 4; ++e) {
    int d = (e * 256 + t) * 16;
    *(uint4*)(outb + d) = *(const uint4*)(st + d);
  }
}

// ---- pre-pass 2: repack W codes into lane-consumable half-word order ----
// Block 256 thr = (kto 8 x r 32); grid = 256 nt x 16 ktg.
__global__ __launch_bounds__(256)
void repack_w(const int* __restrict__ pw, char* __restrict__ bws) {
  const int nt  = blockIdx.x & 255;
  const int ktg = blockIdx.x >> 8;
  const int r   = threadIdx.x & 31;
  const int kto = threadIdx.x >> 5;
  const int kt  = ktg * 8 + kto;
  const int n   = nt * 32 + r;
  int4 wv = *(const int4*)(pw + (size_t)n * KP + kt * 4);
  uint32_t lo01 = __builtin_amdgcn_perm((uint32_t)wv.y, (uint32_t)wv.x, 0x05040100u);
  uint32_t hi01 = __builtin_amdgcn_perm((uint32_t)wv.y, (uint32_t)wv.x, 0x07060302u);
  uint32_t lo23 = __builtin_amdgcn_perm((uint32_t)wv.w, (uint32_t)wv.z, 0x05040100u);
  uint32_t hi23 = __builtin_amdgcn_perm((uint32_t)wv.w, (uint32_t)wv.z, 0x07060302u);
  char* base = bws + ((size_t)nt * 128 + kt) * 512;
  *(uint2*)(base + r * 8)       = make_uint2(lo01, lo23);   // half 0 (codes k 0-7)
  *(uint2*)(base + 256 + r * 8) = make_uint2(hi01, hi23);   // half 1 (codes k 8-15)
}

// ====== fast path: NO LDS, NO BARRIER. 64-thr wave-blocks, 64x64 tile each ======
__global__ __launch_bounds__(64, 2)
void ternary_gemm_nb(const char* __restrict__ xhT,
                     const char* __restrict__ bws,
                     const float* __restrict__ bias,
                     float*       __restrict__ out) {
  const int lane  = threadIdx.x;
  const int bid   = blockIdx.x;
  // XCD swizzle: bid&7 -> m-pair, so each XCD keeps a 2 MiB A-slab hot in L2.
  const int m_idx = ((bid & 7) << 1) | ((bid >> 3) & 1);   // 0..15
  const int n_idx = bid >> 4;                              // 0..127
  const int m0 = m_idx * 64, n0 = n_idx * 64;

  // A frag pointers: i -> i32 = (m_idx&1)*2 + i; fragment ks at +ks*1024
  const char* pA[2];
#pragma unroll
  for (int i = 0; i < 2; ++i)
    pA[i] = xhT + (size_t)(m_idx >> 1) * MT_STRIDE + ((m_idx & 1) * 2 + i) * 4096 + lane * 16;

  // B half-word pointers: j -> nt = n_idx*2 + j; 512 B per tile, lane*8 coalesced
  const char* pB[2];
#pragma unroll
  for (int j = 0; j < 2; ++j)
    pB[j] = bws + ((size_t)(n_idx * 2 + j) * 128) * 512 + lane * 8;

  f32x16 acc[2][2];
#pragma unroll
  for (int i = 0; i < 2; ++i)
#pragma unroll
    for (int j = 0; j < 2; ++j) acc[i][j] = (f32x16)(0.f);

  const int NT = K_DIM / BK;   // 128

  // Prologue: load tile 0 into the A-set
  half8 aA[2][4], aB[2][4];
  uint2 bA[2], bB[2];
#pragma unroll
  for (int i = 0; i < 2; ++i)
#pragma unroll
    for (int ks = 0; ks < 4; ++ks)
      aA[i][ks] = *(const half8*)(pA[i] + ks * 1024);
#pragma unroll
  for (int j = 0; j < 2; ++j) bA[j] = *(const uint2*)(pB[j]);
#pragma unroll
  for (int i = 0; i < 2; ++i) pA[i] += KT_STRIDE;
#pragma unroll
  for (int j = 0; j < 2; ++j) pB[j] += 512;

  auto STEP = [&](half8 (&aC)[2][4], uint2 (&bC)[2],
                  half8 (&aN)[2][4], uint2 (&bN)[2], int kt) {
    // Prefetch tile kt+1 (registers; in flight across the whole compute phase)
#pragma unroll
    for (int i = 0; i < 2; ++i)
#pragma unroll
      for (int ks = 0; ks < 4; ++ks)
        aN[i][ks] = *(const half8*)(pA[i] + ks * 1024);
#pragma unroll
    for (int j = 0; j < 2; ++j) bN[j] = *(const uint2*)(pB[j]);
    if (kt < NT - 2) {
#pragma unroll
      for (int i = 0; i < 2; ++i) pA[i] += KT_STRIDE;
#pragma unroll
      for (int j = 0; j < 2; ++j) pB[j] += 512;
    }
    // Decode + MFMA, tile kt
#pragma unroll
    for (int ks = 0; ks < 4; ++ks) {
      uint32_t h0 = (ks & 2) ? (uint32_t)bC[0].y : (uint32_t)bC[0].x;
      uint32_t h1 = (ks & 2) ? (uint32_t)bC[1].y : (uint32_t)bC[1].x;
      h0 = (ks & 1) ? (h0 >> 16) : (h0 & 0xFFFFu);
      h1 = (ks & 1) ? (h1 >> 16) : (h1 & 0xFFFFu);
      half8 bf0 = dec_h(h0);
      half8 bf1 = dec_h(h1);
      acc[0][0] = __builtin_amdgcn_mfma_f32_32x32x16_f16(aC[0][ks], bf0, acc[0][0], 0, 0, 0);
      acc[0][1] = __builtin_amdgcn_mfma_f32_32x32x16_f16(aC[0][ks], bf1, acc[0][1], 0, 0, 0);
      acc[1][0] = __builtin_amdgcn_mfma_f32_32x32x16_f16(aC[1][ks], bf0, acc[1][0], 0, 0, 0);
      acc[1][1] = __builtin_amdgcn_mfma_f32_32x32x16_f16(aC[1][ks], bf1, acc[1][1], 0, 0, 0);
    }
  };

  for (int kt = 0; kt < NT; kt += 2) {   // ping-pong: no register copies
    STEP(aA, bA, aB, bB, kt);
    STEP(aB, bB, aA, bA, kt + 1);
  }

  // Epilogue: 32x32 C/D (m74/m101): col(n)=lane&31, row(m)=(reg&3)+8*(reg>>2)+4*(lane>>5)
  // fp16 rounding replicated exactly: f16(y) + f16(bias) in half, widen to f32.
#pragma unroll
  for (int j = 0; j < 2; ++j) {
    int n = n0 + j * 32 + (lane & 31);
    __half hb = __float2half_rn(bias[n]);
#pragma unroll
    for (int i = 0; i < 2; ++i) {
      int mbase = m0 + i * 32 + 4 * (lane >> 5);
#pragma unroll
      for (int reg = 0; reg < 16; ++reg) {
        int m = mbase + (reg & 3) + 8 * (reg >> 2);
        __half hy = __float2half_rn(acc[i][j][reg]);
        out[(size_t)m * N_DIM + n] = __half2float(__hadd(hy, hb));
      }
    }
  }
}

// ====== tier-2 (R9, known-good, needs 16 MiB ws): decode-at-consumer, word LDS stage ======
__device__ __forceinline__ half8 dec_frag(uint32_t word, uint32_t sh) {
  return dec_h((word >> sh) & 0xFFFFu);
}

__global__ __launch_bounds__(256, 2)
void ternary_gemm_dc(const char* __restrict__ xhT,
                     const int*  __restrict__ pw,
                     const float* __restrict__ bias,
                     float*       __restrict__ out) {
  __shared__ __align__(16) char stg[2 * 2048];

  const int tid  = threadIdx.x;
  const int lane = tid & 63;
  const int w    = tid >> 6;
  const int wm   = w >> 1, wn = w & 1;
  const int bid  = blockIdx.x;
  const int mt   = bid & 7;
  const int bm   = mt * 128;
  const int bn   = (bid >> 3) * 128;

  const char* pA[2];
#pragma unroll
  for (int i = 0; i < 2; ++i)
    pA[i] = xhT + (size_t)mt * MT_STRIDE + (wm * 2 + i) * 4096 + lane * 16;

  const int rT = tid >> 1, hT = tid & 1;
  const int2* gB = (const int2*)pw + (size_t)(bn + rT) * (KP / 2) + hT;
  const int stOff = rT * 16 + hT * 8;

  int rowOff[2];
#pragma unroll
  for (int j = 0; j < 2; ++j)
    rowOff[j] = (wn * 64 + j * 32 + (lane & 31)) * 16;
  const uint32_t sh = (lane >> 5) * 16;

  f32x16 acc[2][2];
#pragma unroll
  for (int i = 0; i < 2; ++i)
#pragma unroll
    for (int j = 0; j < 2; ++j) acc[i][j] = (f32x16)(0.f);

  const int NT = K_DIM / BK;

  *(int2*)(stg + stOff) = gB[0];
  half8 aA[2][4], aB[2][4];
#pragma unroll
  for (int i = 0; i < 2; ++i)
#pragma unroll
    for (int ks = 0; ks < 4; ++ks)
      aA[i][ks] = *(const half8*)(pA[i] + ks * 1024);
#pragma unroll
  for (int i = 0; i < 2; ++i) pA[i] += KT_STRIDE;
  int2 wcur = gB[2];
  __syncthreads();

  auto step = [&](half8 (&aC)[2][4], half8 (&aN)[2][4], int cur, int kt) {
#pragma unroll
    for (int i = 0; i < 2; ++i)
#pragma unroll
      for (int ks = 0; ks < 4; ++ks)
        aN[i][ks] = *(const half8*)(pA[i] + ks * 1024);
    if (kt < NT - 2) {
#pragma unroll
      for (int i = 0; i < 2; ++i) pA[i] += KT_STRIDE;
    }
    int kn2 = (kt + 2 < NT) ? (kt + 2) : (NT - 1);
    int2 wnxt = gB[kn2 * 2];

    uint32_t wr0[4], wr1[4];
    *(uint4*)wr0 = *(const uint4*)(stg + cur * 2048 + rowOff[0]);
    *(uint4*)wr1 = *(const uint4*)(stg + cur * 2048 + rowOff[1]);
    *(int2*)(stg + (cur ^ 1) * 2048 + stOff) = wcur;

#pragma unroll
    for (int ks = 0; ks < 4; ++ks) {
      half8 bf0 = dec_frag(wr0[ks], sh);
      half8 bf1 = dec_frag(wr1[ks], sh);
      acc[0][0] = __builtin_amdgcn_mfma_f32_32x32x16_f16(aC[0][ks], bf0, acc[0][0], 0, 0, 0);
      acc[0][1] = __builtin_amdgcn_mfma_f32_32x32x16_f16(aC[0][ks], bf1, acc[0][1], 0, 0, 0);
      acc[1][0] = __builtin_amdgcn_mfma_f32_32x32x16_f16(aC[1][ks], bf0, acc[1][0], 0, 0, 0);
      acc[1][1] = __builtin_amdgcn_mfma_f32_32x32x16_f16(aC[1][ks], bf1, acc[1][1], 0, 0, 0);
    }
    __syncthreads();
    wcur = wnxt;
  };

  for (int kt = 0; kt < NT; kt += 2) {
    step(aA, aB, 0, kt);
    step(aB, aA, 1, kt + 1);
  }

#pragma unroll
  for (int j = 0; j < 2; ++j) {
    int n = bn + wn * 64 + j * 32 + (lane & 31);
    __half hb = __float2half_rn(bias[n]);
#pragma unroll
    for (int i = 0; i < 2; ++i) {
      int mbase = bm + wm * 64 + i * 32 + 4 * (lane >> 5);
#pragma unroll
      for (int reg = 0; reg < 16; ++reg) {
        int m = mbase + (reg & 3) + 8 * (reg >> 2);
        __half hy = __float2half_rn(acc[i][j][reg]);
        out[(size_t)m * N_DIM + n] = __half2float(__hadd(hy, hb));
      }
    }
  }
}

// ================= tier-3 fallback (R4, known-good, no ws) =================
__device__ __forceinline__ uint32_t unpack_pair16(uint32_t u, int p) {
  uint32_t c0 = (u >> (4 * p)) & 3u;
  uint32_t c1 = (u >> (4 * p + 2)) & 3u;
  uint32_t lo = (c0 & 1u) * 0x3C00u + (c0 >> 1) * 0x0600u;
  uint32_t hi = (c1 & 1u) * 0x3C00u + (c1 >> 1) * 0x0600u;
  return lo | (hi << 16);
}

__global__ __launch_bounds__(256, 2)
void ternary_gemm(const float* __restrict__ x,
                  const int*   __restrict__ pw,
                  const float* __restrict__ bias,
                  float*       __restrict__ out) {
  __shared__ __align__(16) char AsB[128 * B_STRIDE];
  __shared__ __align__(16) char BsB[128 * B_STRIDE];

  const int tid  = threadIdx.x;
  const int lane = tid & 63;
  const int w    = tid >> 6;
  const int wm   = w >> 1, wn = w & 1;
  const int bid  = blockIdx.x;
  const int bm   = (bid & 7) * 128;
  const int bn   = (bid >> 3) * 128;

  const int rT = tid >> 1, hT = tid & 1;
  const float* gA = x + (size_t)(bm + rT) * K_DIM + hT * 32;
  char* const  lA = AsB + rT * B_STRIDE + hT * 64;
  const int2* gB = (const int2*)pw + (size_t)(bn + rT) * (KP / 2) + hT;
  char* dBp[4];
#pragma unroll
  for (int h = 0; h < 4; ++h)
    dBp[h] = BsB + rT * B_STRIDE + (hT * 4 + h) * 16;

  int offA[4][2], offB[4][2];
#pragma unroll
  for (int i = 0; i < 4; ++i)
#pragma unroll
    for (int ks = 0; ks < 2; ++ks) {
      int c = ks * 4 + (lane >> 4);
      offA[i][ks] = (wm * 64 + i * 16 + (lane & 15)) * B_STRIDE + c * 16;
      offB[i][ks] = (wn * 64 + i * 16 + (lane & 15)) * B_STRIDE + c * 16;
    }

  f32x4 acc[4][4];
#pragma unroll
  for (int i = 0; i < 4; ++i)
#pragma unroll
    for (int j = 0; j < 4; ++j)
      acc[i][j] = (f32x4){0.f, 0.f, 0.f, 0.f};

  const int NT = K_DIM / BK;
  for (int kt = 0; kt < NT; ++kt) {
    __syncthreads();
    int2 wcur = gB[kt * 2];
    float4 av[8];
#pragma unroll
    for (int v = 0; v < 8; ++v) av[v] = *(const float4*)(gA + kt * BK + v * 4);
    uint32_t d0[8], d1[8];
#pragma unroll
    for (int p = 0; p < 8; ++p) d0[p] = unpack_pair16((uint32_t)wcur.x, p);
#pragma unroll
    for (int p = 0; p < 8; ++p) d1[p] = unpack_pair16((uint32_t)wcur.y, p);
    *(uint4*)dBp[0] = make_uint4(d0[0], d0[1], d0[2], d0[3]);
    *(uint4*)dBp[1] = make_uint4(d0[4], d0[5], d0[6], d0[7]);
    *(uint4*)dBp[2] = make_uint4(d1[0], d1[1], d1[2], d1[3]);
    *(uint4*)dBp[3] = make_uint4(d1[4], d1[5], d1[6], d1[7]);
#pragma unroll
    for (int v = 0; v < 4; ++v) {
      uint4 aw;
      aw.x = cvt2(av[2 * v].x, av[2 * v].y);
      aw.y = cvt2(av[2 * v].z, av[2 * v].w);
      aw.z = cvt2(av[2 * v + 1].x, av[2 * v + 1].y);
      aw.w = cvt2(av[2 * v + 1].z, av[2 * v + 1].w);
      *(uint4*)(lA + v * 16) = aw;
    }
    __syncthreads();
#pragma unroll
    for (int ks = 0; ks < 2; ++ks) {
      half8 af[4], bf[4];
#pragma unroll
      for (int i = 0; i < 4; ++i) af[i] = *(const half8*)(AsB + offA[i][ks]);
#pragma unroll
      for (int j = 0; j < 4; ++j) bf[j] = *(const half8*)(BsB + offB[j][ks]);
#pragma unroll
      for (int i = 0; i < 4; ++i)
#pragma unroll
        for (int j = 0; j < 4; ++j)
          acc[i][j] = __builtin_amdgcn_mfma_f32_16x16x32_f16(af[i], bf[j], acc[i][j], 0, 0, 0);
    }
  }
#pragma unroll
  for (int j = 0; j < 4; ++j) {
    int n = bn + wn * 64 + j * 16 + (lane & 15);
    __half hb = __float2half_rn(bias[n]);
#pragma unroll
    for (int i = 0; i < 4; ++i) {
      int m0 = bm + wm * 64 + i * 16 + (lane >> 4) * 4;
#pragma unroll
      for (int r = 0; r < 4; ++r) {
        __half hy = __float2half_rn(acc[i][j][r]);
        out[(size_t)(m0 + r) * N_DIM + n] = __half2float(__hadd(hy, hb));
      }
    }
  }
}

extern "C" void kernel_launch(void* const* d_in, const int* in_sizes, int n_in,
                              void* d_out, int out_size, void* d_ws, size_t ws_size,
                              hipStream_t stream) {
  (void)in_sizes; (void)n_in; (void)out_size;
  const float* x    = (const float*)d_in[0];
  const int*   pwp  = (const int*)d_in[1];
  const float* bias = (const float*)d_in[2];
  float*       outp = (float*)d_out;

  const size_t need1 = (size_t)M_DIM * K_DIM * 2;          // 16 MiB (A)
  const size_t need2 = need1 + (size_t)16 * 1024 * 1024;   // +16 MiB (repacked W)
  if (ws_size >= need2) {
    char* xhT = (char*)d_ws;
    char* bws = (char*)d_ws + BW_OFF;
    cvt_x_t<<<8 * 128, 256, 0, stream>>>(x, xhT);
    repack_w<<<256 * 16, 256, 0, stream>>>(pwp, bws);
    ternary_gemm_nb<<<2048, 64, 0, stream>>>(xhT, bws, bias, outp);
  } else if (ws_size >= need1) {
    char* xhT = (char*)d_ws;
    cvt_x_t<<<8 * 128, 256, 0, stream>>>(x, xhT);
    ternary_gemm_dc<<<512, 256, 0, stream>>>(xhT, pwp, bias, outp);
  } else {
    ternary_gemm<<<512, 256, 0, stream>>>(x, pwp, bias, outp);
  }
}